// Round 16
// baseline (374.767 us; speedup 1.0000x reference)
//
#include <hip/hip_runtime.h>

#define N_NODES 20000
#define E_EDGES 640000
#define F_DIM 128
#define RBF_DIM 64
#define T_TYPES 5
#define NSEG (N_NODES * T_TYPES)
#define EPB 128   // edges per tile (edge kernel; 2 tiles per block)
#define MTS 136   // msgT row stride (ushorts) — R13-verified

typedef __attribute__((ext_vector_type(8))) short short8;
typedef __attribute__((ext_vector_type(4))) float f32x4;

__device__ __forceinline__ float silu_f(float x) { return x / (1.0f + __expf(-x)); }

__device__ __forceinline__ ushort f2bf(float f) {
  unsigned u = __float_as_uint(f);
  u += 0x7fffu + ((u >> 16) & 1u);
  return (ushort)(u >> 16);
}
__device__ __forceinline__ float bf2f(ushort u) {
  return __uint_as_float(((unsigned)u) << 16);
}
// packed fp32->bf16 (RTNE): src0 -> D[15:0], src1 -> D[31:16]
__device__ __forceinline__ unsigned cvt_pk(float lo, float hi) {
  unsigned r;
  asm("v_cvt_pk_bf16_f32 %0, %1, %2" : "=v"(r) : "v"(lo), "v"(hi));
  return r;
}
union S8U4 {
  short8 s;
  unsigned u[4];
};

// ------- weight prep (fp32->bf16) + hist zeroing -------
__global__ __launch_bounds__(256) void prep_kernel(
    const float* __restrict__ w1, const float* __restrict__ w2,
    const float* __restrict__ qw, const float* __restrict__ kw,
    const float* __restrict__ vw, const float* __restrict__ o1w,
    const float* __restrict__ o2w, const float* __restrict__ lw,
    ushort* __restrict__ w1b, ushort* __restrict__ w2b,
    ushort* __restrict__ qwb, ushort* __restrict__ kwb,
    ushort* __restrict__ vwb, ushort* __restrict__ o1wb,
    ushort* __restrict__ o2wb, ushort* __restrict__ lwb,
    int* __restrict__ hist) {
  int i = blockIdx.x * 256 + threadIdx.x;
  if (i < F_DIM * RBF_DIM) w1b[i] = f2bf(w1[i]);
  if (i < F_DIM * F_DIM) {
    w2b[i] = f2bf(w2[i]);
    qwb[i] = f2bf(qw[i]);
    kwb[i] = f2bf(kw[i]);
    vwb[i] = f2bf(vw[i]);
    o1wb[i] = f2bf(o1w[i]);
    o2wb[i] = f2bf(o2w[i]);
    lwb[i] = f2bf(lw[i]);
  }
  for (int j = i; j < NSEG; j += 64 * 256) hist[j] = 0;
}

// ------- stage1: hist+rank + y-zero (blocks 0..2499) | lin1 MFMA (2500..) ---
__global__ __launch_bounds__(256) void stage1_kernel(
    const int* __restrict__ srcp, const int* __restrict__ dstp,
    const int* __restrict__ z, int* __restrict__ hist, int* __restrict__ rnk,
    float* __restrict__ y, const float* __restrict__ x,
    const ushort* __restrict__ lwb, ushort* __restrict__ xlb) {
  const int b = blockIdx.x;
  const int tid = threadIdx.x;
  if (b < E_EDGES / 256) {
    int e = b * 256 + tid;
    int s = srcp[e];
    int seg = dstp[e] * T_TYPES + z[s];
    rnk[e] = atomicAdd(&hist[seg], 1);
    float4* yz = (float4*)(y + (size_t)b * 5120);
#pragma unroll
    for (int i = 0; i < 5; ++i)
      yz[tid + i * 256] = make_float4(0.f, 0.f, 0.f, 0.f);
  } else {
    const int lane = tid & 63;
    const int w = tid >> 6;
    const int lr = lane & 15, lh = lane >> 4;
    const int r0 = (b - E_EDGES / 256) * 80;

    f32x4 acc[5][2] = {};
#pragma unroll
    for (int ksi = 0; ksi < 4; ++ksi) {
      short8 B[2];
#pragma unroll
      for (int fc = 0; fc < 2; ++fc)
        B[fc] = *(const short8*)(lwb + (size_t)(w * 32 + fc * 16 + lr) * 128 +
                                 ksi * 32 + lh * 8);
#pragma unroll
      for (int fm = 0; fm < 5; ++fm) {
        const float* ap =
            x + (size_t)(r0 + fm * 16 + lr) * 128 + ksi * 32 + lh * 8;
        float4 a0 = *(const float4*)ap;
        float4 a1 = *(const float4*)(ap + 4);
        S8U4 t;
        t.u[0] = cvt_pk(a0.x, a0.y);
        t.u[1] = cvt_pk(a0.z, a0.w);
        t.u[2] = cvt_pk(a1.x, a1.y);
        t.u[3] = cvt_pk(a1.z, a1.w);
#pragma unroll
        for (int fc = 0; fc < 2; ++fc)
          acc[fm][fc] = __builtin_amdgcn_mfma_f32_16x16x32_bf16(
              t.s, B[fc], acc[fm][fc], 0, 0, 0);
      }
    }
#pragma unroll
    for (int fm = 0; fm < 5; ++fm)
#pragma unroll
      for (int fc = 0; fc < 2; ++fc)
#pragma unroll
        for (int rp = 0; rp < 4; rp += 2) {
          int rrow = fm * 16 + lh * 4 + rp;
          int col = w * 32 + fc * 16 + lr;
          unsigned u = cvt_pk(acc[fm][fc][rp], acc[fm][fc][rp + 1]);
          xlb[(size_t)(r0 + rrow) * 128 + col] = (ushort)u;
          xlb[(size_t)(r0 + rrow + 1) * 128 + col] = (ushort)(u >> 16);
        }
  }
}

__global__ __launch_bounds__(256) void scan1_kernel(const int* __restrict__ hist,
                                                    int* __restrict__ offs,
                                                    int* __restrict__ bsums) {
  __shared__ int lds[256];
  int tid = threadIdx.x;
  int base = blockIdx.x * 1024 + tid * 4;
  int v[4];
  int s = 0;
#pragma unroll
  for (int i = 0; i < 4; ++i) {
    v[i] = (base + i < NSEG) ? hist[base + i] : 0;
    s += v[i];
  }
  lds[tid] = s;
  __syncthreads();
  for (int d = 1; d < 256; d <<= 1) {
    int t = (tid >= d) ? lds[tid - d] : 0;
    __syncthreads();
    lds[tid] += t;
    __syncthreads();
  }
  int excl = lds[tid] - s;
#pragma unroll
  for (int i = 0; i < 4; ++i) {
    if (base + i < NSEG) offs[base + i] = excl;
    excl += v[i];
  }
  if (tid == 255) bsums[blockIdx.x] = lds[255];
}

// scatter + inline bsums prefix (scan2 folded in) + sorted staging precompute
__global__ __launch_bounds__(256) void scatter_kernel(
    const int* __restrict__ srcp, const int* __restrict__ dstp,
    const int* __restrict__ z, const float* __restrict__ ewp,
    const int* __restrict__ offs, const int* __restrict__ bsums,
    const int* __restrict__ rnk, int* __restrict__ perm,
    int* __restrict__ ssegS, int* __restrict__ srcS,
    float* __restrict__ sCS) {
  __shared__ int pb[128];
  const int tid = threadIdx.x;
  const int NB_SCAN = (NSEG + 1023) / 1024;  // 98
  if (tid < 128) pb[tid] = (tid < NB_SCAN) ? bsums[tid] : 0;
  __syncthreads();
  int vown = (tid < 128) ? pb[tid] : 0;
  for (int d = 1; d < 128; d <<= 1) {
    int t = (tid >= d && tid < 128) ? pb[tid - d] : 0;
    __syncthreads();
    if (tid < 128) pb[tid] += t;
    __syncthreads();
  }
  if (tid < 128) pb[tid] -= vown;  // exclusive prefix
  __syncthreads();

  int e = blockIdx.x * 256 + tid;
  int s = srcp[e];
  int seg = dstp[e] * T_TYPES + z[s];
  int pos = offs[seg] + pb[seg >> 10] + rnk[e];
  perm[pos] = e;
  ssegS[pos] = seg;
  srcS[pos] = s * 128;
  float wd = ewp[e];
  float c = 0.5f * (__cosf(wd * 0.6283185307179586f) + 1.0f);
  sCS[pos] = (wd < 5.0f) ? c : 0.0f;
}

// ---- per-edge filter net (MFMA, sorted), 2 tiles/block with EA prefetch ----
// Tile-1 EA rows issued as raw loads before tile-0 MFMAs; converted after.
__global__ __launch_bounds__(256, 3) void edge_mfma_kernel(
    const float* __restrict__ edge_attr, const int* __restrict__ perm,
    const int* __restrict__ ssegS, const int* __restrict__ srcS,
    const float* __restrict__ sCS, const ushort* __restrict__ w1b,
    const float* __restrict__ b1, const ushort* __restrict__ w2b,
    const float* __restrict__ b2, const ushort* __restrict__ xlb,
    float* __restrict__ y) {
  __shared__ ushort hs[128 * MTS];
  __shared__ float sC[256];
  __shared__ int srcoff[256];  // src*128
  __shared__ int sseg[256];
  __shared__ unsigned long long smask[2];

  const int tid = threadIdx.x;
  const int e0 = blockIdx.x * 256;  // 2 tiles: [e0, e0+128), [e0+128, e0+256)
  const int lane = tid & 63;
  const int w = tid >> 6;
  const int wm = w >> 1, wn = w & 1;
  const int lr = lane & 15, lh = lane >> 4;

  // staging for both tiles (coalesced from sorted arrays)
  {
    int p = e0 + tid;
    srcoff[tid] = srcS[p];
    sseg[tid] = ssegS[p];
    sC[tid] = sCS[p];
  }

  int prowA[4], prowB[4];
#pragma unroll
  for (int fm = 0; fm < 4; ++fm) {
    prowA[fm] = perm[e0 + wm * 64 + fm * 16 + lr];
    prowB[fm] = perm[e0 + 128 + wm * 64 + fm * 16 + lr];
  }

  float rb1[4], rb2[4];
#pragma unroll
  for (int fc = 0; fc < 4; ++fc) {
    int n = wn * 64 + fc * 16 + lr;
    rb1[fc] = b1[n];
    rb2[fc] = b2[n];
  }

  // ---- T0 A-fragments (load + cvt) ----
  short8 af0[2][4];
#pragma unroll
  for (int ks = 0; ks < 2; ++ks)
#pragma unroll
    for (int fm = 0; fm < 4; ++fm) {
      const float* ap = edge_attr + (size_t)prowA[fm] * 64 + ks * 32 + lh * 8;
      float4 a0 = *(const float4*)ap;
      float4 a1 = *(const float4*)(ap + 4);
      S8U4 t;
      t.u[0] = cvt_pk(a0.x, a0.y);
      t.u[1] = cvt_pk(a0.z, a0.w);
      t.u[2] = cvt_pk(a1.x, a1.y);
      t.u[3] = cvt_pk(a1.z, a1.w);
      af0[ks][fm] = t.s;
    }

  // ---- T1 raw prefetch: issue now, convert after T0 GEMM1 MFMAs ----
  float4 rB[2][4][2];
#pragma unroll
  for (int ks = 0; ks < 2; ++ks)
#pragma unroll
    for (int fm = 0; fm < 4; ++fm) {
      const float* ap = edge_attr + (size_t)prowB[fm] * 64 + ks * 32 + lh * 8;
      rB[ks][fm][0] = *(const float4*)ap;
      rB[ks][fm][1] = *(const float4*)(ap + 4);
    }

  auto gemm1 = [&](const short8 (&af)[2][4], f32x4 (&acc)[4][4]) {
#pragma unroll
    for (int ks = 0; ks < 2; ++ks) {
      short8 bfr[4];
#pragma unroll
      for (int fc = 0; fc < 4; ++fc)
        bfr[fc] = *(const short8*)(w1b + (size_t)(wn * 64 + fc * 16 + lr) * 64 +
                                   ks * 32 + lh * 8);
#pragma unroll
      for (int fm = 0; fm < 4; ++fm)
#pragma unroll
        for (int fc = 0; fc < 4; ++fc)
          acc[fm][fc] = __builtin_amdgcn_mfma_f32_16x16x32_bf16(
              af[ks][fm], bfr[fc], acc[fm][fc], 0, 0, 0);
    }
  };

  f32x4 acc0[4][4] = {};
  gemm1(af0, acc0);

  // convert T1 prefetch (loads overlapped with T0 GEMM1)
  short8 afB[2][4];
#pragma unroll
  for (int ks = 0; ks < 2; ++ks)
#pragma unroll
    for (int fm = 0; fm < 4; ++fm) {
      S8U4 t;
      t.u[0] = cvt_pk(rB[ks][fm][0].x, rB[ks][fm][0].y);
      t.u[1] = cvt_pk(rB[ks][fm][0].z, rB[ks][fm][0].w);
      t.u[2] = cvt_pk(rB[ks][fm][1].x, rB[ks][fm][1].y);
      t.u[3] = cvt_pk(rB[ks][fm][1].z, rB[ks][fm][1].w);
      afB[ks][fm] = t.s;
    }

  // rest-of-tile: ep1 -> GEMM2 -> ep2 -> reduce  (tb = tile base 0 or 128)
  auto rest = [&](f32x4 (&a)[4][4], int tb) {
    __syncthreads();  // staging visible / previous tile's reduce done

    if (tid < EPB) {
      int head = (tid == 0) || (sseg[tb + tid] != sseg[tb + tid - 1]);
      unsigned long long m = __ballot(head);
      if ((tid & 63) == 0) smask[tid >> 6] = m;
    }

    // ep1: silu+bias -> swizzled hs
#pragma unroll
    for (int fm = 0; fm < 4; ++fm) {
#pragma unroll
      for (int fc = 0; fc < 4; ++fc) {
#pragma unroll
        for (int rp = 0; rp < 4; rp += 2) {
          int ml0 = wm * 64 + fm * 16 + lh * 4 + rp;
          int ml1 = ml0 + 1;
          int n = wn * 64 + fc * 16 + lr;
          float h0 = silu_f(a[fm][fc][rp] + rb1[fc]);
          float h1 = silu_f(a[fm][fc][rp + 1] + rb1[fc]);
          unsigned u = cvt_pk(h0, h1);
          hs[(ml0 * 256 + ((n * 2) ^ ((ml0 & 7) << 4))) >> 1] = (ushort)u;
          hs[(ml1 * 256 + ((n * 2) ^ ((ml1 & 7) << 4))) >> 1] = (ushort)(u >> 16);
        }
      }
    }
    __syncthreads();  // hs(h) ready

    // GEMM2: W = h @ w2^T
    f32x4 acc2[4][4] = {};
#pragma unroll
    for (int ks = 0; ks < 4; ++ks) {
      const int k0 = ks * 32;
      short8 af[4], bfr[4];
#pragma unroll
      for (int fm = 0; fm < 4; ++fm) {
        int ml = wm * 64 + fm * 16 + lr;
        int byte_in_row = (k0 * 2 + lh * 16) ^ ((ml & 7) << 4);
        af[fm] = *(const short8*)&hs[(ml * 256 + byte_in_row) >> 1];
      }
#pragma unroll
      for (int fc = 0; fc < 4; ++fc)
        bfr[fc] = *(const short8*)(w2b + (size_t)(wn * 64 + fc * 16 + lr) * 128 +
                                   k0 + lh * 8);
#pragma unroll
      for (int fm = 0; fm < 4; ++fm)
#pragma unroll
        for (int fc = 0; fc < 4; ++fc)
          acc2[fm][fc] = __builtin_amdgcn_mfma_f32_16x16x32_bf16(
              af[fm], bfr[fc], acc2[fm][fc], 0, 0, 0);
    }
    __syncthreads();  // hs(h) reads done; buffer becomes msgT

    // ep2: msg = (W + b2) * C -> msgT[col][row]
#pragma unroll
    for (int fm = 0; fm < 4; ++fm) {
#pragma unroll
      for (int rp = 0; rp < 4; rp += 2) {
        int ml0 = wm * 64 + fm * 16 + lh * 4 + rp;
        float c0 = sC[tb + ml0], c1 = sC[tb + ml0 + 1];
#pragma unroll
        for (int fc = 0; fc < 4; ++fc) {
          int n = wn * 64 + fc * 16 + lr;
          float v0 = (acc2[fm][fc][rp] + rb2[fc]) * c0;
          float v1 = (acc2[fm][fc][rp + 1] + rb2[fc]) * c1;
          *(unsigned*)&hs[n * MTS + ml0] = cvt_pk(v0, v1);
        }
      }
    }
    __syncthreads();  // msgT + smask ready

    // reduce: interior runs plain stores, chain ends atomic
    {
      int cp = tid & 63;
      int q = tid >> 6;
      int rbase = q * 32;
      int c0 = cp * 2;
      unsigned mm = (unsigned)(smask[q >> 1] >> ((q & 1) * 32));
      float a0 = 0.0f, a1 = 0.0f;
      int cur = sseg[tb + rbase];
      bool first = true;
#pragma unroll
      for (int it = 0; it < 4; ++it) {
        int r0 = rbase + it * 8;
        short8 m0 = *(const short8*)&hs[c0 * MTS + r0];
        short8 m1 = *(const short8*)&hs[(c0 + 1) * MTS + r0];
        unsigned xv[8];
#pragma unroll
        for (int j = 0; j < 8; ++j)
          xv[j] = *(const unsigned*)&xlb[(size_t)srcoff[tb + r0 + j] + c0];
#pragma unroll
        for (int j = 0; j < 8; ++j) {
          int rr = it * 8 + j;
          if (rr && ((mm >> rr) & 1u)) {
            float* yp = &y[(size_t)cur * 128 + c0];
            if (first) {
              atomicAdd(yp, a0);
              atomicAdd(yp + 1, a1);
              first = false;
            } else {
              yp[0] = a0;
              yp[1] = a1;
            }
            a0 = a1 = 0.0f;
            cur = sseg[tb + r0 + j];
          }
          a0 += bf2f((ushort)m0[j]) * bf2f((ushort)xv[j]);
          a1 += bf2f((ushort)m1[j]) * bf2f((ushort)(xv[j] >> 16));
        }
      }
      float* yp = &y[(size_t)cur * 128 + c0];
      atomicAdd(yp, a0);
      atomicAdd(yp + 1, a1);
    }
  };

  rest(acc0, 0);

  // T1 GEMM1 (register-only; overlaps tail of T0 reduce before the sync)
  f32x4 acc1[4][4] = {};
  gemm1(afB, acc1);
  rest(acc1, 128);
}

// -- fused qkv (MFMA) + attention + slot-sum + o1 (MFMA) + o2 (MFMA) -> out --
#define QS 136  // padded LDS row stride (ushorts), 272B = 16B-aligned rows
#define NB 16   // nodes per block
__global__ __launch_bounds__(256) void attn_out_kernel(
    const float* __restrict__ y, const int* __restrict__ hist,
    const ushort* __restrict__ qwb, const ushort* __restrict__ kwb,
    const ushort* __restrict__ vwb, const float* __restrict__ qb,
    const float* __restrict__ kb, const float* __restrict__ vb,
    const ushort* __restrict__ o1wb, const float* __restrict__ o1b,
    const ushort* __restrict__ o2wb, const float* __restrict__ o2b,
    float* __restrict__ outp) {
  __shared__ ushort bufA[80 * QS];  // q -> v -> t1(bf16)
  __shared__ ushort bufB[80 * QS];  // k -> s(bf16)
  __shared__ float aap[NB * 8 * 2 * 5];  // partial scores [n][h][g][j]
  __shared__ float pmv[80];
  __shared__ float snpm[NB];
  __shared__ float sxb[3][128];

  const int tid = threadIdx.x;
  // bijective XCD swizzle: 1250 blocks = 2 XCDs x 157 + 6 XCDs x 156
  const int xcd = blockIdx.x & 7;
  const int loc = blockIdx.x >> 3;
  const int bid = (xcd < 2 ? xcd * 157 : 314 + (xcd - 2) * 156) + loc;
  const int n0 = bid * NB;
  const int row0 = n0 * T_TYPES;
  const int lane = tid & 63;
  const int w = tid >> 6;  // wave 0..3 -> col slice w*32
  const int lr = lane & 15, lh = lane >> 4;

  if (tid < 128) {
    sxb[0][tid] = qb[tid];
    sxb[1][tid] = kb[tid];
    sxb[2][tid] = vb[tid];
  }
  if (tid < 80) pmv[tid] = (hist[(size_t)row0 + tid] > 0) ? 1.0f : 0.0f;

  // A fragments (y rows fp32 -> bf16), reused across q/k/v
  short8 A[4][5];
#pragma unroll
  for (int ksi = 0; ksi < 4; ++ksi) {
#pragma unroll
    for (int fm = 0; fm < 5; ++fm) {
      const float* ap =
          y + (size_t)(row0 + fm * 16 + lr) * 128 + ksi * 32 + lh * 8;
      float4 a0 = *(const float4*)ap;
      float4 a1 = *(const float4*)(ap + 4);
      S8U4 t;
      t.u[0] = cvt_pk(a0.x, a0.y);
      t.u[1] = cvt_pk(a0.z, a0.w);
      t.u[2] = cvt_pk(a1.x, a1.y);
      t.u[3] = cvt_pk(a1.z, a1.w);
      A[ksi][fm] = t.s;
    }
  }
  __syncthreads();  // biases/pmv staged
  if (tid < NB) {
    float s = 0.0f;
#pragma unroll
    for (int t = 0; t < 5; ++t) s += pmv[tid * 5 + t];
    snpm[tid] = s;
  }

  auto do_proj = [&](const ushort* __restrict__ Wb, const float* bias_row,
                     ushort* __restrict__ dst) {
    f32x4 acc[5][2] = {};
#pragma unroll
    for (int ksi = 0; ksi < 4; ++ksi) {
      short8 B[2];
#pragma unroll
      for (int fc = 0; fc < 2; ++fc)
        B[fc] = *(const short8*)(Wb + (size_t)(w * 32 + fc * 16 + lr) * 128 +
                                 ksi * 32 + lh * 8);
#pragma unroll
      for (int fm = 0; fm < 5; ++fm)
#pragma unroll
        for (int fc = 0; fc < 2; ++fc)
          acc[fm][fc] = __builtin_amdgcn_mfma_f32_16x16x32_bf16(
              A[ksi][fm], B[fc], acc[fm][fc], 0, 0, 0);
    }
#pragma unroll
    for (int fm = 0; fm < 5; ++fm)
#pragma unroll
      for (int fc = 0; fc < 2; ++fc)
#pragma unroll
        for (int rp = 0; rp < 4; rp += 2) {
          int rrow = fm * 16 + lh * 4 + rp;
          int col = w * 32 + fc * 16 + lr;
          float v0 = acc[fm][fc][rp] + bias_row[col];
          float v1 = acc[fm][fc][rp + 1] + bias_row[col];
          unsigned u = cvt_pk(v0, v1);
          dst[rrow * QS + col] = (ushort)u;
          dst[(rrow + 1) * QS + col] = (ushort)(u >> 16);
        }
  };

  do_proj(qwb, sxb[0], bufA);
  do_proj(kwb, sxb[1], bufB);
  __syncthreads();

  // scores (all 256 threads): thread = (n, h, g); g splits the i-loop 3/2
  {
    int n = tid >> 4, h = (tid >> 1) & 7, g = tid & 1;
    int i0 = g ? 3 : 0;
    int cnt = g ? 2 : 3;
    float kv[5][16];
#pragma unroll
    for (int j = 0; j < 5; ++j) {
      short8 v0 = *(const short8*)&bufB[(n * 5 + j) * QS + h * 16];
      short8 v1 = *(const short8*)&bufB[(n * 5 + j) * QS + h * 16 + 8];
#pragma unroll
      for (int d = 0; d < 8; ++d) {
        kv[j][d] = bf2f((ushort)v0[d]);
        kv[j][d + 8] = bf2f((ushort)v1[d]);
      }
    }
    float a[5] = {};
    for (int ii = 0; ii < cnt; ++ii) {
      int i = i0 + ii;
      float qv[16];
      short8 q0 = *(const short8*)&bufA[(n * 5 + i) * QS + h * 16];
      short8 q1 = *(const short8*)&bufA[(n * 5 + i) * QS + h * 16 + 8];
#pragma unroll
      for (int d = 0; d < 8; ++d) {
        qv[d] = bf2f((ushort)q0[d]);
        qv[d + 8] = bf2f((ushort)q1[d]);
      }
      float pmi = pmv[n * 5 + i];
#pragma unroll
      for (int j = 0; j < 5; ++j) {
        float dd = 0.0f;
#pragma unroll
        for (int d = 0; d < 16; ++d) dd += qv[d] * kv[j][d];
        a[j] += pmi * silu_f(dd);
      }
    }
#pragma unroll
    for (int j = 0; j < 5; ++j) aap[((n * 8 + h) * 2 + g) * 5 + j] = a[j];
  }
  __syncthreads();  // scores done; bufA (q) dead

  do_proj(vwb, sxb[2], bufA);  // v overwrites q
  __syncthreads();

  // PV: s[n][f0..f0+7] -> bufB as bf16 [16][QS] (k dead)
  {
    int n = tid >> 4;
    int o = tid & 15;
    int f0 = o * 8;
    int h = f0 >> 4;
    float acc8[8] = {};
#pragma unroll
    for (int j = 0; j < 5; ++j) {
      float a = (aap[((n * 8 + h) * 2 + 0) * 5 + j] +
                 aap[((n * 8 + h) * 2 + 1) * 5 + j]) *
                pmv[n * 5 + j];
      short8 vv8 = *(const short8*)&bufA[(n * 5 + j) * QS + f0];
#pragma unroll
      for (int d = 0; d < 8; ++d) acc8[d] += a * bf2f((ushort)vv8[d]);
    }
    S8U4 t;
    t.u[0] = cvt_pk(acc8[0], acc8[1]);
    t.u[1] = cvt_pk(acc8[2], acc8[3]);
    t.u[2] = cvt_pk(acc8[4], acc8[5]);
    t.u[3] = cvt_pk(acc8[6], acc8[7]);
    *(short8*)&bufB[n * QS + f0] = t.s;
  }
  __syncthreads();  // s(bf16) ready; bufA (v) dead

  // o1 (MFMA): t1 = s @ o1w^T + npm*o1b -> bufA bf16 [16][QS]
  {
    f32x4 acc[2] = {};
#pragma unroll
    for (int ksi = 0; ksi < 4; ++ksi) {
      short8 af = *(const short8*)&bufB[lr * QS + ksi * 32 + lh * 8];
      short8 B0 = *(const short8*)(o1wb + (size_t)(w * 32 + lr) * 128 +
                                   ksi * 32 + lh * 8);
      short8 B1 = *(const short8*)(o1wb + (size_t)(w * 32 + 16 + lr) * 128 +
                                   ksi * 32 + lh * 8);
      acc[0] = __builtin_amdgcn_mfma_f32_16x16x32_bf16(af, B0, acc[0], 0, 0, 0);
      acc[1] = __builtin_amdgcn_mfma_f32_16x16x32_bf16(af, B1, acc[1], 0, 0, 0);
    }
#pragma unroll
    for (int fc = 0; fc < 2; ++fc) {
      int col = w * 32 + fc * 16 + lr;
      float bb = o1b[col];
#pragma unroll
      for (int r = 0; r < 4; ++r) {
        int row = lh * 4 + r;
        bufA[row * QS + col] = f2bf(acc[fc][r] + snpm[row] * bb);
      }
    }
  }
  __syncthreads();

  // o2 (MFMA): out = silu(t1 @ o2w^T + o2b) -> global
  {
    f32x4 acc[2] = {};
#pragma unroll
    for (int ksi = 0; ksi < 4; ++ksi) {
      short8 af = *(const short8*)&bufA[lr * QS + ksi * 32 + lh * 8];
      short8 B0 = *(const short8*)(o2wb + (size_t)(w * 32 + lr) * 128 +
                                   ksi * 32 + lh * 8);
      short8 B1 = *(const short8*)(o2wb + (size_t)(w * 32 + 16 + lr) * 128 +
                                   ksi * 32 + lh * 8);
      acc[0] = __builtin_amdgcn_mfma_f32_16x16x32_bf16(af, B0, acc[0], 0, 0, 0);
      acc[1] = __builtin_amdgcn_mfma_f32_16x16x32_bf16(af, B1, acc[1], 0, 0, 0);
    }
#pragma unroll
    for (int fc = 0; fc < 2; ++fc) {
      int col = w * 32 + fc * 16 + lr;
      float bb = o2b[col];
#pragma unroll
      for (int r = 0; r < 4; ++r) {
        int row = lh * 4 + r;
        outp[(size_t)(n0 + row) * 128 + col] = silu_f(acc[fc][r] + bb);
      }
    }
  }
}

extern "C" void kernel_launch(void* const* d_in, const int* in_sizes, int n_in,
                              void* d_out, int out_size, void* d_ws, size_t ws_size,
                              hipStream_t stream) {
  const float* x = (const float*)d_in[0];
  const int* z = (const int*)d_in[1];
  const int* ei = (const int*)d_in[2];
  const float* ew = (const float*)d_in[3];
  const float* ea = (const float*)d_in[4];
  const float* lin1_w = (const float*)d_in[5];
  const float* fw1 = (const float*)d_in[6];
  const float* fb1 = (const float*)d_in[7];
  const float* fw2 = (const float*)d_in[8];
  const float* fb2 = (const float*)d_in[9];
  const float* qw = (const float*)d_in[10];
  const float* qb = (const float*)d_in[11];
  const float* kw = (const float*)d_in[12];
  const float* kb = (const float*)d_in[13];
  const float* vw = (const float*)d_in[14];
  const float* vb = (const float*)d_in[15];
  const float* o1w = (const float*)d_in[16];
  const float* o1b = (const float*)d_in[17];
  const float* o2w = (const float*)d_in[18];
  const float* o2b = (const float*)d_in[19];
  float* outp = (float*)d_out;
  float* ws = (float*)d_ws;

  float* y = ws;                                      // NSEG*F fp32
  ushort* xlb = (ushort*)(y + (size_t)NSEG * F_DIM);  // N*F bf16
  ushort* w1b = xlb + (size_t)N_NODES * F_DIM;
  ushort* w2b = w1b + F_DIM * RBF_DIM;
  ushort* qwb = w2b + F_DIM * F_DIM;
  ushort* kwb = qwb + F_DIM * F_DIM;
  ushort* vwb = kwb + F_DIM * F_DIM;
  ushort* o1wb = vwb + F_DIM * F_DIM;
  ushort* o2wb = o1wb + F_DIM * F_DIM;
  ushort* lwb = o2wb + F_DIM * F_DIM;
  int* hist = (int*)(lwb + F_DIM * F_DIM);
  int* offs = hist + NSEG;
  int* bsums = offs + NSEG;
  int* rnk = bsums + 128;
  int* perm = rnk + E_EDGES;
  int* ssegS = perm + E_EDGES;
  int* srcS = ssegS + E_EDGES;
  float* sCS = (float*)(srcS + E_EDGES);

  const int* srcp = ei;
  const int* dstp = ei + E_EDGES;
  const int NB_SCAN = (NSEG + 1023) / 1024;  // 98

  prep_kernel<<<64, 256, 0, stream>>>(fw1, fw2, qw, kw, vw, o1w, o2w, lin1_w,
                                      w1b, w2b, qwb, kwb, vwb, o1wb, o2wb, lwb,
                                      hist);
  stage1_kernel<<<E_EDGES / 256 + N_NODES / 80, 256, 0, stream>>>(
      srcp, dstp, z, hist, rnk, y, x, lwb, xlb);
  scan1_kernel<<<NB_SCAN, 256, 0, stream>>>(hist, offs, bsums);
  scatter_kernel<<<E_EDGES / 256, 256, 0, stream>>>(
      srcp, dstp, z, ew, offs, bsums, rnk, perm, ssegS, srcS, sCS);
  edge_mfma_kernel<<<E_EDGES / 256, 256, 0, stream>>>(
      ea, perm, ssegS, srcS, sCS, w1b, fb1, w2b, fb2, xlb, y);
  attn_out_kernel<<<N_NODES / NB, 256, 0, stream>>>(y, hist, qwb, kwb, vwb, qb,
                                                    kb, vb, o1wb, o1b, o2wb,
                                                    o2b, outp);
}

// Round 17
// 290.850 us; speedup vs baseline: 1.2885x; 1.2885x over previous
//
#include <hip/hip_runtime.h>

#define N_NODES 20000
#define E_EDGES 640000
#define F_DIM 128
#define RBF_DIM 64
#define T_TYPES 5
#define NSEG (N_NODES * T_TYPES)
#define EPB 128   // edges per block (edge kernel)
#define MTS 136   // msgT row stride (ushorts) — R13-verified

typedef __attribute__((ext_vector_type(8))) short short8;
typedef __attribute__((ext_vector_type(4))) float f32x4;

__device__ __forceinline__ float silu_f(float x) { return x / (1.0f + __expf(-x)); }

__device__ __forceinline__ ushort f2bf(float f) {
  unsigned u = __float_as_uint(f);
  u += 0x7fffu + ((u >> 16) & 1u);
  return (ushort)(u >> 16);
}
__device__ __forceinline__ float bf2f(ushort u) {
  return __uint_as_float(((unsigned)u) << 16);
}
// packed fp32->bf16 (RTNE): src0 -> D[15:0], src1 -> D[31:16]
__device__ __forceinline__ unsigned cvt_pk(float lo, float hi) {
  unsigned r;
  asm("v_cvt_pk_bf16_f32 %0, %1, %2" : "=v"(r) : "v"(lo), "v"(hi));
  return r;
}
union S8U4 {
  short8 s;
  unsigned u[4];
};

// ------- weight prep (fp32->bf16) + hist zeroing -------
__global__ __launch_bounds__(256) void prep_kernel(
    const float* __restrict__ w1, const float* __restrict__ w2,
    const float* __restrict__ qw, const float* __restrict__ kw,
    const float* __restrict__ vw, const float* __restrict__ o1w,
    const float* __restrict__ o2w, const float* __restrict__ lw,
    ushort* __restrict__ w1b, ushort* __restrict__ w2b,
    ushort* __restrict__ qwb, ushort* __restrict__ kwb,
    ushort* __restrict__ vwb, ushort* __restrict__ o1wb,
    ushort* __restrict__ o2wb, ushort* __restrict__ lwb,
    int* __restrict__ hist) {
  int i = blockIdx.x * 256 + threadIdx.x;
  if (i < F_DIM * RBF_DIM) w1b[i] = f2bf(w1[i]);
  if (i < F_DIM * F_DIM) {
    w2b[i] = f2bf(w2[i]);
    qwb[i] = f2bf(qw[i]);
    kwb[i] = f2bf(kw[i]);
    vwb[i] = f2bf(vw[i]);
    o1wb[i] = f2bf(o1w[i]);
    o2wb[i] = f2bf(o2w[i]);
    lwb[i] = f2bf(lw[i]);
  }
  for (int j = i; j < NSEG; j += 64 * 256) hist[j] = 0;
}

// ------- stage1: hist+rank + y-zero (blocks 0..2499) | lin1 MFMA (2500..) ---
__global__ __launch_bounds__(256) void stage1_kernel(
    const int* __restrict__ srcp, const int* __restrict__ dstp,
    const int* __restrict__ z, int* __restrict__ hist, int* __restrict__ rnk,
    float* __restrict__ y, const float* __restrict__ x,
    const ushort* __restrict__ lwb, ushort* __restrict__ xlb) {
  const int b = blockIdx.x;
  const int tid = threadIdx.x;
  if (b < E_EDGES / 256) {
    int e = b * 256 + tid;
    int s = srcp[e];
    int seg = dstp[e] * T_TYPES + z[s];
    rnk[e] = atomicAdd(&hist[seg], 1);
    float4* yz = (float4*)(y + (size_t)b * 5120);
#pragma unroll
    for (int i = 0; i < 5; ++i)
      yz[tid + i * 256] = make_float4(0.f, 0.f, 0.f, 0.f);
  } else {
    const int lane = tid & 63;
    const int w = tid >> 6;
    const int lr = lane & 15, lh = lane >> 4;
    const int r0 = (b - E_EDGES / 256) * 80;

    f32x4 acc[5][2] = {};
#pragma unroll
    for (int ksi = 0; ksi < 4; ++ksi) {
      short8 B[2];
#pragma unroll
      for (int fc = 0; fc < 2; ++fc)
        B[fc] = *(const short8*)(lwb + (size_t)(w * 32 + fc * 16 + lr) * 128 +
                                 ksi * 32 + lh * 8);
#pragma unroll
      for (int fm = 0; fm < 5; ++fm) {
        const float* ap =
            x + (size_t)(r0 + fm * 16 + lr) * 128 + ksi * 32 + lh * 8;
        float4 a0 = *(const float4*)ap;
        float4 a1 = *(const float4*)(ap + 4);
        S8U4 t;
        t.u[0] = cvt_pk(a0.x, a0.y);
        t.u[1] = cvt_pk(a0.z, a0.w);
        t.u[2] = cvt_pk(a1.x, a1.y);
        t.u[3] = cvt_pk(a1.z, a1.w);
#pragma unroll
        for (int fc = 0; fc < 2; ++fc)
          acc[fm][fc] = __builtin_amdgcn_mfma_f32_16x16x32_bf16(
              t.s, B[fc], acc[fm][fc], 0, 0, 0);
      }
    }
#pragma unroll
    for (int fm = 0; fm < 5; ++fm)
#pragma unroll
      for (int fc = 0; fc < 2; ++fc)
#pragma unroll
        for (int rp = 0; rp < 4; rp += 2) {
          int rrow = fm * 16 + lh * 4 + rp;
          int col = w * 32 + fc * 16 + lr;
          unsigned u = cvt_pk(acc[fm][fc][rp], acc[fm][fc][rp + 1]);
          xlb[(size_t)(r0 + rrow) * 128 + col] = (ushort)u;
          xlb[(size_t)(r0 + rrow + 1) * 128 + col] = (ushort)(u >> 16);
        }
  }
}

__global__ __launch_bounds__(256) void scan1_kernel(const int* __restrict__ hist,
                                                    int* __restrict__ offs,
                                                    int* __restrict__ bsums) {
  __shared__ int lds[256];
  int tid = threadIdx.x;
  int base = blockIdx.x * 1024 + tid * 4;
  int v[4];
  int s = 0;
#pragma unroll
  for (int i = 0; i < 4; ++i) {
    v[i] = (base + i < NSEG) ? hist[base + i] : 0;
    s += v[i];
  }
  lds[tid] = s;
  __syncthreads();
  for (int d = 1; d < 256; d <<= 1) {
    int t = (tid >= d) ? lds[tid - d] : 0;
    __syncthreads();
    lds[tid] += t;
    __syncthreads();
  }
  int excl = lds[tid] - s;
#pragma unroll
  for (int i = 0; i < 4; ++i) {
    if (base + i < NSEG) offs[base + i] = excl;
    excl += v[i];
  }
  if (tid == 255) bsums[blockIdx.x] = lds[255];
}

// scatter + inline bsums prefix (scan2 folded in) + sorted staging precompute
__global__ __launch_bounds__(256) void scatter_kernel(
    const int* __restrict__ srcp, const int* __restrict__ dstp,
    const int* __restrict__ z, const float* __restrict__ ewp,
    const int* __restrict__ offs, const int* __restrict__ bsums,
    const int* __restrict__ rnk, int* __restrict__ perm,
    int* __restrict__ ssegS, int* __restrict__ srcS,
    float* __restrict__ sCS) {
  __shared__ int pb[128];
  const int tid = threadIdx.x;
  const int NB_SCAN = (NSEG + 1023) / 1024;  // 98
  if (tid < 128) pb[tid] = (tid < NB_SCAN) ? bsums[tid] : 0;
  __syncthreads();
  int vown = (tid < 128) ? pb[tid] : 0;
  for (int d = 1; d < 128; d <<= 1) {
    int t = (tid >= d && tid < 128) ? pb[tid - d] : 0;
    __syncthreads();
    if (tid < 128) pb[tid] += t;
    __syncthreads();
  }
  if (tid < 128) pb[tid] -= vown;  // exclusive prefix
  __syncthreads();

  int e = blockIdx.x * 256 + tid;
  int s = srcp[e];
  int seg = dstp[e] * T_TYPES + z[s];
  int pos = offs[seg] + pb[seg >> 10] + rnk[e];
  perm[pos] = e;
  ssegS[pos] = seg;
  srcS[pos] = s * 128;
  float wd = ewp[e];
  float c = 0.5f * (__cosf(wd * 0.6283185307179586f) + 1.0f);
  sCS[pos] = (wd < 5.0f) ? c : 0.0f;
}

// ---- per-edge filter net (MFMA, sorted) + transposed-msg bitmask reduce ----
// (FROZEN R13 structure — MTS=136, EPB=128, 4 blocks/CU; 163 us verified)
__global__ __launch_bounds__(256, 4) void edge_mfma_kernel(
    const float* __restrict__ edge_attr, const int* __restrict__ perm,
    const int* __restrict__ ssegS, const int* __restrict__ srcS,
    const float* __restrict__ sCS, const ushort* __restrict__ w1b,
    const float* __restrict__ b1, const ushort* __restrict__ w2b,
    const float* __restrict__ b2, const ushort* __restrict__ xlb,
    float* __restrict__ y) {
  __shared__ ushort hs[128 * MTS];
  __shared__ float sC[EPB];
  __shared__ int srcoff[EPB];  // src*128
  __shared__ int sseg[EPB];
  __shared__ unsigned long long smask[2];

  const int tid = threadIdx.x;
  const int e0 = blockIdx.x * EPB;
  const int lane = tid & 63;
  const int w = tid >> 6;
  const int wm = w >> 1, wn = w & 1;
  const int lr = lane & 15, lh = lane >> 4;

  int prow[4];
#pragma unroll
  for (int fm = 0; fm < 4; ++fm) prow[fm] = perm[e0 + wm * 64 + fm * 16 + lr];

  float rb1[4], rb2[4];
#pragma unroll
  for (int fc = 0; fc < 4; ++fc) {
    int n = wn * 64 + fc * 16 + lr;
    rb1[fc] = b1[n];
    rb2[fc] = b2[n];
  }

  if (tid < EPB) {
    int p = e0 + tid;
    srcoff[tid] = srcS[p];
    sseg[tid] = ssegS[p];
    sC[tid] = sCS[p];
  }

  f32x4 acc[4][4] = {};
#pragma unroll
  for (int ks = 0; ks < 2; ++ks) {
    const int k0 = ks * 32;
    short8 af[4], bfr[4];
#pragma unroll
    for (int fm = 0; fm < 4; ++fm) {
      const float* ap = edge_attr + (size_t)prow[fm] * 64 + k0 + lh * 8;
      float4 a0 = *(const float4*)ap;
      float4 a1 = *(const float4*)(ap + 4);
      S8U4 t;
      t.u[0] = cvt_pk(a0.x, a0.y);
      t.u[1] = cvt_pk(a0.z, a0.w);
      t.u[2] = cvt_pk(a1.x, a1.y);
      t.u[3] = cvt_pk(a1.z, a1.w);
      af[fm] = t.s;
    }
#pragma unroll
    for (int fc = 0; fc < 4; ++fc)
      bfr[fc] = *(const short8*)(w1b + (size_t)(wn * 64 + fc * 16 + lr) * 64 +
                                 k0 + lh * 8);
#pragma unroll
    for (int fm = 0; fm < 4; ++fm)
#pragma unroll
      for (int fc = 0; fc < 4; ++fc)
        acc[fm][fc] = __builtin_amdgcn_mfma_f32_16x16x32_bf16(
            af[fm], bfr[fc], acc[fm][fc], 0, 0, 0);
  }

#pragma unroll
  for (int fm = 0; fm < 4; ++fm) {
#pragma unroll
    for (int fc = 0; fc < 4; ++fc) {
#pragma unroll
      for (int rp = 0; rp < 4; rp += 2) {
        int ml0 = wm * 64 + fm * 16 + lh * 4 + rp;
        int ml1 = ml0 + 1;
        int n = wn * 64 + fc * 16 + lr;
        float h0 = silu_f(acc[fm][fc][rp] + rb1[fc]);
        float h1 = silu_f(acc[fm][fc][rp + 1] + rb1[fc]);
        unsigned u = cvt_pk(h0, h1);
        hs[(ml0 * 256 + ((n * 2) ^ ((ml0 & 7) << 4))) >> 1] = (ushort)u;
        hs[(ml1 * 256 + ((n * 2) ^ ((ml1 & 7) << 4))) >> 1] = (ushort)(u >> 16);
      }
    }
  }
  __syncthreads();  // B2

  if (tid < EPB) {
    int head = (tid == 0) || (sseg[tid] != sseg[tid - 1]);
    unsigned long long m = __ballot(head);
    if ((tid & 63) == 0) smask[tid >> 6] = m;
  }

  f32x4 acc2[4][4] = {};
#pragma unroll
  for (int ks = 0; ks < 4; ++ks) {
    const int k0 = ks * 32;
    short8 af[4], bfr[4];
#pragma unroll
    for (int fm = 0; fm < 4; ++fm) {
      int ml = wm * 64 + fm * 16 + lr;
      int byte_in_row = (k0 * 2 + lh * 16) ^ ((ml & 7) << 4);
      af[fm] = *(const short8*)&hs[(ml * 256 + byte_in_row) >> 1];
    }
#pragma unroll
    for (int fc = 0; fc < 4; ++fc)
      bfr[fc] = *(const short8*)(w2b + (size_t)(wn * 64 + fc * 16 + lr) * 128 +
                                 k0 + lh * 8);
#pragma unroll
    for (int fm = 0; fm < 4; ++fm)
#pragma unroll
      for (int fc = 0; fc < 4; ++fc)
        acc2[fm][fc] = __builtin_amdgcn_mfma_f32_16x16x32_bf16(
            af[fm], bfr[fc], acc2[fm][fc], 0, 0, 0);
  }
  __syncthreads();  // B3

#pragma unroll
  for (int fm = 0; fm < 4; ++fm) {
#pragma unroll
    for (int rp = 0; rp < 4; rp += 2) {
      int ml0 = wm * 64 + fm * 16 + lh * 4 + rp;
      float c0 = sC[ml0], c1 = sC[ml0 + 1];
#pragma unroll
      for (int fc = 0; fc < 4; ++fc) {
        int n = wn * 64 + fc * 16 + lr;
        float v0 = (acc2[fm][fc][rp] + rb2[fc]) * c0;
        float v1 = (acc2[fm][fc][rp + 1] + rb2[fc]) * c1;
        *(unsigned*)&hs[n * MTS + ml0] = cvt_pk(v0, v1);
      }
    }
  }
  __syncthreads();  // B4

  {
    int cp = tid & 63;
    int q = tid >> 6;
    int rbase = q * 32;
    int c0 = cp * 2;
    unsigned mm = (unsigned)(smask[q >> 1] >> ((q & 1) * 32));
    float a0 = 0.0f, a1 = 0.0f;
    int cur = sseg[rbase];
    bool first = true;
#pragma unroll
    for (int it = 0; it < 4; ++it) {
      int r0 = rbase + it * 8;
      short8 m0 = *(const short8*)&hs[c0 * MTS + r0];
      short8 m1 = *(const short8*)&hs[(c0 + 1) * MTS + r0];
      unsigned xv[8];
#pragma unroll
      for (int j = 0; j < 8; ++j)
        xv[j] = *(const unsigned*)&xlb[(size_t)srcoff[r0 + j] + c0];
#pragma unroll
      for (int j = 0; j < 8; ++j) {
        int rr = it * 8 + j;
        if (rr && ((mm >> rr) & 1u)) {
          float* yp = &y[(size_t)cur * 128 + c0];
          if (first) {
            atomicAdd(yp, a0);
            atomicAdd(yp + 1, a1);
            first = false;
          } else {
            yp[0] = a0;
            yp[1] = a1;
          }
          a0 = a1 = 0.0f;
          cur = sseg[r0 + j];
        }
        a0 += bf2f((ushort)m0[j]) * bf2f((ushort)xv[j]);
        a1 += bf2f((ushort)m1[j]) * bf2f((ushort)(xv[j] >> 16));
      }
    }
    float* yp = &y[(size_t)cur * 128 + c0];
    atomicAdd(yp, a0);
    atomicAdd(yp + 1, a1);
  }
}

// -- fused qkv (MFMA) + attention + slot-sum + o1 (MFMA) + o2 (MFMA) -> out --
#define QS 136  // padded LDS row stride (ushorts), 272B = 16B-aligned rows
#define NB 16   // nodes per block
__global__ __launch_bounds__(256) void attn_out_kernel(
    const float* __restrict__ y, const int* __restrict__ hist,
    const ushort* __restrict__ qwb, const ushort* __restrict__ kwb,
    const ushort* __restrict__ vwb, const float* __restrict__ qb,
    const float* __restrict__ kb, const float* __restrict__ vb,
    const ushort* __restrict__ o1wb, const float* __restrict__ o1b,
    const ushort* __restrict__ o2wb, const float* __restrict__ o2b,
    float* __restrict__ outp) {
  __shared__ ushort bufA[80 * QS];  // q -> v -> t1(bf16)
  __shared__ ushort bufB[80 * QS];  // k -> s(bf16)
  __shared__ float aap[NB * 8 * 2 * 5];  // partial scores [n][h][g][j]
  __shared__ float pmv[80];
  __shared__ float snpm[NB];
  __shared__ float sxb[3][128];

  const int tid = threadIdx.x;
  // bijective XCD swizzle: 1250 blocks = 2 XCDs x 157 + 6 XCDs x 156
  const int xcd = blockIdx.x & 7;
  const int loc = blockIdx.x >> 3;
  const int bid = (xcd < 2 ? xcd * 157 : 314 + (xcd - 2) * 156) + loc;
  const int n0 = bid * NB;
  const int row0 = n0 * T_TYPES;
  const int lane = tid & 63;
  const int w = tid >> 6;  // wave 0..3 -> col slice w*32
  const int lr = lane & 15, lh = lane >> 4;

  if (tid < 128) {
    sxb[0][tid] = qb[tid];
    sxb[1][tid] = kb[tid];
    sxb[2][tid] = vb[tid];
  }
  if (tid < 80) pmv[tid] = (hist[(size_t)row0 + tid] > 0) ? 1.0f : 0.0f;

  // A fragments (y rows fp32 -> bf16), reused across q/k/v
  short8 A[4][5];
#pragma unroll
  for (int ksi = 0; ksi < 4; ++ksi) {
#pragma unroll
    for (int fm = 0; fm < 5; ++fm) {
      const float* ap =
          y + (size_t)(row0 + fm * 16 + lr) * 128 + ksi * 32 + lh * 8;
      float4 a0 = *(const float4*)ap;
      float4 a1 = *(const float4*)(ap + 4);
      S8U4 t;
      t.u[0] = cvt_pk(a0.x, a0.y);
      t.u[1] = cvt_pk(a0.z, a0.w);
      t.u[2] = cvt_pk(a1.x, a1.y);
      t.u[3] = cvt_pk(a1.z, a1.w);
      A[ksi][fm] = t.s;
    }
  }
  __syncthreads();  // biases/pmv staged
  if (tid < NB) {
    float s = 0.0f;
#pragma unroll
    for (int t = 0; t < 5; ++t) s += pmv[tid * 5 + t];
    snpm[tid] = s;
  }

  auto do_proj = [&](const ushort* __restrict__ Wb, const float* bias_row,
                     ushort* __restrict__ dst) {
    f32x4 acc[5][2] = {};
#pragma unroll
    for (int ksi = 0; ksi < 4; ++ksi) {
      short8 B[2];
#pragma unroll
      for (int fc = 0; fc < 2; ++fc)
        B[fc] = *(const short8*)(Wb + (size_t)(w * 32 + fc * 16 + lr) * 128 +
                                 ksi * 32 + lh * 8);
#pragma unroll
      for (int fm = 0; fm < 5; ++fm)
#pragma unroll
        for (int fc = 0; fc < 2; ++fc)
          acc[fm][fc] = __builtin_amdgcn_mfma_f32_16x16x32_bf16(
              A[ksi][fm], B[fc], acc[fm][fc], 0, 0, 0);
    }
#pragma unroll
    for (int fm = 0; fm < 5; ++fm)
#pragma unroll
      for (int fc = 0; fc < 2; ++fc)
#pragma unroll
        for (int rp = 0; rp < 4; rp += 2) {
          int rrow = fm * 16 + lh * 4 + rp;
          int col = w * 32 + fc * 16 + lr;
          float v0 = acc[fm][fc][rp] + bias_row[col];
          float v1 = acc[fm][fc][rp + 1] + bias_row[col];
          unsigned u = cvt_pk(v0, v1);
          dst[rrow * QS + col] = (ushort)u;
          dst[(rrow + 1) * QS + col] = (ushort)(u >> 16);
        }
  };

  do_proj(qwb, sxb[0], bufA);
  do_proj(kwb, sxb[1], bufB);
  __syncthreads();

  // scores (all 256 threads): thread = (n, h, g); g splits the i-loop 3/2
  {
    int n = tid >> 4, h = (tid >> 1) & 7, g = tid & 1;
    int i0 = g ? 3 : 0;
    int cnt = g ? 2 : 3;
    float kv[5][16];
#pragma unroll
    for (int j = 0; j < 5; ++j) {
      short8 v0 = *(const short8*)&bufB[(n * 5 + j) * QS + h * 16];
      short8 v1 = *(const short8*)&bufB[(n * 5 + j) * QS + h * 16 + 8];
#pragma unroll
      for (int d = 0; d < 8; ++d) {
        kv[j][d] = bf2f((ushort)v0[d]);
        kv[j][d + 8] = bf2f((ushort)v1[d]);
      }
    }
    float a[5] = {};
    for (int ii = 0; ii < cnt; ++ii) {
      int i = i0 + ii;
      float qv[16];
      short8 q0 = *(const short8*)&bufA[(n * 5 + i) * QS + h * 16];
      short8 q1 = *(const short8*)&bufA[(n * 5 + i) * QS + h * 16 + 8];
#pragma unroll
      for (int d = 0; d < 8; ++d) {
        qv[d] = bf2f((ushort)q0[d]);
        qv[d + 8] = bf2f((ushort)q1[d]);
      }
      float pmi = pmv[n * 5 + i];
#pragma unroll
      for (int j = 0; j < 5; ++j) {
        float dd = 0.0f;
#pragma unroll
        for (int d = 0; d < 16; ++d) dd += qv[d] * kv[j][d];
        a[j] += pmi * silu_f(dd);
      }
    }
#pragma unroll
    for (int j = 0; j < 5; ++j) aap[((n * 8 + h) * 2 + g) * 5 + j] = a[j];
  }
  __syncthreads();  // scores done; bufA (q) dead

  do_proj(vwb, sxb[2], bufA);  // v overwrites q
  __syncthreads();

  // PV: s[n][f0..f0+7] -> bufB as bf16 [16][QS] (k dead)
  {
    int n = tid >> 4;
    int o = tid & 15;
    int f0 = o * 8;
    int h = f0 >> 4;
    float acc8[8] = {};
#pragma unroll
    for (int j = 0; j < 5; ++j) {
      float a = (aap[((n * 8 + h) * 2 + 0) * 5 + j] +
                 aap[((n * 8 + h) * 2 + 1) * 5 + j]) *
                pmv[n * 5 + j];
      short8 vv8 = *(const short8*)&bufA[(n * 5 + j) * QS + f0];
#pragma unroll
      for (int d = 0; d < 8; ++d) acc8[d] += a * bf2f((ushort)vv8[d]);
    }
    S8U4 t;
    t.u[0] = cvt_pk(acc8[0], acc8[1]);
    t.u[1] = cvt_pk(acc8[2], acc8[3]);
    t.u[2] = cvt_pk(acc8[4], acc8[5]);
    t.u[3] = cvt_pk(acc8[6], acc8[7]);
    *(short8*)&bufB[n * QS + f0] = t.s;
  }
  __syncthreads();  // s(bf16) ready; bufA (v) dead

  // o1 (MFMA): t1 = s @ o1w^T + npm*o1b -> bufA bf16 [16][QS]
  {
    f32x4 acc[2] = {};
#pragma unroll
    for (int ksi = 0; ksi < 4; ++ksi) {
      short8 af = *(const short8*)&bufB[lr * QS + ksi * 32 + lh * 8];
      short8 B0 = *(const short8*)(o1wb + (size_t)(w * 32 + lr) * 128 +
                                   ksi * 32 + lh * 8);
      short8 B1 = *(const short8*)(o1wb + (size_t)(w * 32 + 16 + lr) * 128 +
                                   ksi * 32 + lh * 8);
      acc[0] = __builtin_amdgcn_mfma_f32_16x16x32_bf16(af, B0, acc[0], 0, 0, 0);
      acc[1] = __builtin_amdgcn_mfma_f32_16x16x32_bf16(af, B1, acc[1], 0, 0, 0);
    }
#pragma unroll
    for (int fc = 0; fc < 2; ++fc) {
      int col = w * 32 + fc * 16 + lr;
      float bb = o1b[col];
#pragma unroll
      for (int r = 0; r < 4; ++r) {
        int row = lh * 4 + r;
        bufA[row * QS + col] = f2bf(acc[fc][r] + snpm[row] * bb);
      }
    }
  }
  __syncthreads();

  // o2 (MFMA): out = silu(t1 @ o2w^T + o2b) -> global
  {
    f32x4 acc[2] = {};
#pragma unroll
    for (int ksi = 0; ksi < 4; ++ksi) {
      short8 af = *(const short8*)&bufA[lr * QS + ksi * 32 + lh * 8];
      short8 B0 = *(const short8*)(o2wb + (size_t)(w * 32 + lr) * 128 +
                                   ksi * 32 + lh * 8);
      short8 B1 = *(const short8*)(o2wb + (size_t)(w * 32 + 16 + lr) * 128 +
                                   ksi * 32 + lh * 8);
      acc[0] = __builtin_amdgcn_mfma_f32_16x16x32_bf16(af, B0, acc[0], 0, 0, 0);
      acc[1] = __builtin_amdgcn_mfma_f32_16x16x32_bf16(af, B1, acc[1], 0, 0, 0);
    }
#pragma unroll
    for (int fc = 0; fc < 2; ++fc) {
      int col = w * 32 + fc * 16 + lr;
      float bb = o2b[col];
#pragma unroll
      for (int r = 0; r < 4; ++r) {
        int row = lh * 4 + r;
        outp[(size_t)(n0 + row) * 128 + col] = silu_f(acc[fc][r] + bb);
      }
    }
  }
}

extern "C" void kernel_launch(void* const* d_in, const int* in_sizes, int n_in,
                              void* d_out, int out_size, void* d_ws, size_t ws_size,
                              hipStream_t stream) {
  const float* x = (const float*)d_in[0];
  const int* z = (const int*)d_in[1];
  const int* ei = (const int*)d_in[2];
  const float* ew = (const float*)d_in[3];
  const float* ea = (const float*)d_in[4];
  const float* lin1_w = (const float*)d_in[5];
  const float* fw1 = (const float*)d_in[6];
  const float* fb1 = (const float*)d_in[7];
  const float* fw2 = (const float*)d_in[8];
  const float* fb2 = (const float*)d_in[9];
  const float* qw = (const float*)d_in[10];
  const float* qb = (const float*)d_in[11];
  const float* kw = (const float*)d_in[12];
  const float* kb = (const float*)d_in[13];
  const float* vw = (const float*)d_in[14];
  const float* vb = (const float*)d_in[15];
  const float* o1w = (const float*)d_in[16];
  const float* o1b = (const float*)d_in[17];
  const float* o2w = (const float*)d_in[18];
  const float* o2b = (const float*)d_in[19];
  float* outp = (float*)d_out;
  float* ws = (float*)d_ws;

  float* y = ws;                                      // NSEG*F fp32
  ushort* xlb = (ushort*)(y + (size_t)NSEG * F_DIM);  // N*F bf16
  ushort* w1b = xlb + (size_t)N_NODES * F_DIM;
  ushort* w2b = w1b + F_DIM * RBF_DIM;
  ushort* qwb = w2b + F_DIM * F_DIM;
  ushort* kwb = qwb + F_DIM * F_DIM;
  ushort* vwb = kwb + F_DIM * F_DIM;
  ushort* o1wb = vwb + F_DIM * F_DIM;
  ushort* o2wb = o1wb + F_DIM * F_DIM;
  ushort* lwb = o2wb + F_DIM * F_DIM;
  int* hist = (int*)(lwb + F_DIM * F_DIM);
  int* offs = hist + NSEG;
  int* bsums = offs + NSEG;
  int* rnk = bsums + 128;
  int* perm = rnk + E_EDGES;
  int* ssegS = perm + E_EDGES;
  int* srcS = ssegS + E_EDGES;
  float* sCS = (float*)(srcS + E_EDGES);

  const int* srcp = ei;
  const int* dstp = ei + E_EDGES;
  const int NB_SCAN = (NSEG + 1023) / 1024;  // 98

  prep_kernel<<<64, 256, 0, stream>>>(fw1, fw2, qw, kw, vw, o1w, o2w, lin1_w,
                                      w1b, w2b, qwb, kwb, vwb, o1wb, o2wb, lwb,
                                      hist);
  stage1_kernel<<<E_EDGES / 256 + N_NODES / 80, 256, 0, stream>>>(
      srcp, dstp, z, hist, rnk, y, x, lwb, xlb);
  scan1_kernel<<<NB_SCAN, 256, 0, stream>>>(hist, offs, bsums);
  scatter_kernel<<<E_EDGES / 256, 256, 0, stream>>>(
      srcp, dstp, z, ew, offs, bsums, rnk, perm, ssegS, srcS, sCS);
  edge_mfma_kernel<<<E_EDGES / EPB, 256, 0, stream>>>(
      ea, perm, ssegS, srcS, sCS, w1b, fb1, w2b, fb2, xlb, y);
  attn_out_kernel<<<N_NODES / NB, 256, 0, stream>>>(y, hist, qwb, kwb, vwb, qb,
                                                    kb, vb, o1wb, o1b, o2wb,
                                                    o2b, outp);
}